// Round 7
// baseline (67.811 us; speedup 1.0000x reference)
//
#include <hip/hip_runtime.h>
#include <hip/hip_bf16.h>
#include <math.h>

#define BB 64
#define HH 80
#define WW 3000
#define RAD 16
#define TW 96             // output columns per strip
#define XSW 68            // Xs words/row: 64 data + 4 pad (68 % 32 == 4 -> b128 bank-spread)
#define HXS 116           // Hxp col stride: 112 raw rows + 4 pad (116 % 32 == 20 -> b128 bank-spread)
#define S_PER_BLK 4       // strips pipelined per block
#define NKGRP 8           // 32 strips / S_PER_BLK
#define NT 1024
#define EPSF 1e-8f

#define XS_WORDS (HH * XSW)             // 5440
#define HXP_OFF  XS_WORDS
#define HXP_WORDS (TW * HXS)            // 11136
#define ICH_OFF  (XS_WORDS + HXP_WORDS) // 16576
#define TOT_WORDS (ICH_OFF + HH)        // 16656 words = 66624 B -> 2 blocks/CU (32/32 waves)

typedef float f32x2 __attribute__((ext_vector_type(2)));
typedef float f32x4 __attribute__((ext_vector_type(4)));

__device__ __forceinline__ float bflo(uint32_t w) { return __uint_as_float(w << 16); }
__device__ __forceinline__ float bfhi(uint32_t w) { return __uint_as_float(w & 0xffff0000u); }
__device__ __forceinline__ uint32_t packbf2(float lo, float hi) {
    union { __hip_bfloat162 h2; uint32_t u; } u;
    u.h2 = __hip_bfloat162(__float2bfloat16(lo), __float2bfloat16(hi));
    return u.u;
}
// unpack a bf16-packed word into f32x2 {lo, hi}; pk_add accumulates both halves
__device__ __forceinline__ f32x2 uw(uint32_t w) {
    f32x2 r; r.x = bflo(w); r.y = bfhi(w); return r;
}

// staged global load of one quad task (id -> row, quad); zero-filled outside [0,WW)
__device__ __forceinline__ float4 stage_one(const float* __restrict__ inb, int id, int c0) {
    const int row = id >> 5;
    const int q   = id & 31;
    const int gc  = c0 - 16 + 4 * q;
    const float* rp = inb + (size_t)row * WW;
    if (gc >= 0 && gc + 4 <= WW) return *(const float4*)(rp + gc);
    float4 v;
    v.x = (gc     >= 0 && gc     < WW) ? rp[gc]     : 0.f;
    v.y = (gc + 1 >= 0 && gc + 1 < WW) ? rp[gc + 1] : 0.f;
    v.z = (gc + 2 >= 0 && gc + 2 < WW) ? rp[gc + 2] : 0.f;
    v.w = (gc + 3 >= 0 && gc + 3 < WW) ? rp[gc + 3] : 0.f;
    return v;
}
__device__ __forceinline__ void xs_write(uint32_t* smem, int id, float4 g) {
    const int row = id >> 5;
    const int q   = id & 31;
    uint2 w2;
    w2.x = packbf2(g.x, g.y);
    w2.y = packbf2(g.z, g.w);
    *(uint2*)(smem + row * XSW + 2 * q) = w2;
}

// compile-time-folding element selectors (named registers only — no arrays/unions)
#define E4(V, J) ((J) == 0 ? (V).x : ((J) == 1 ? (V).y : ((J) == 2 ? (V).z : (V).w)))
#define W20(Q) E4((Q) < 4 ? v0 : (Q) < 8 ? v1 : (Q) < 12 ? v2 : (Q) < 16 ? v3 : v4, (Q) & 3)
#define W40(Q) E4((Q) < 4 ? v0 : (Q) < 8 ? v1 : (Q) < 12 ? v2 : (Q) < 16 ? v3 : (Q) < 20 ? v4 : \
                  (Q) < 24 ? v5 : (Q) < 28 ? v6 : (Q) < 32 ? v7 : (Q) < 36 ? v8 : v9, (Q) & 3)
#define XP(K) ((K) == 0 ? xp0 : (K) == 1 ? xp1 : (K) == 2 ? xp2 : (K) == 3 ? xp3 : \
               (K) == 4 ? xp4 : (K) == 5 ? xp5 : (K) == 6 ? xp6 : xp7)

__global__ __launch_bounds__(NT, 8)
void localnorm_kernel(const float* __restrict__ in, float* __restrict__ out) {
    extern __shared__ uint32_t smem[];
    uint32_t* Hxp = smem + HXP_OFF;          // Hxp[col][raw_r] at col*HXS + raw_r; raw_r = logical+16
    float* inv_ch = (float*)(smem + ICH_OFF);

    const int t      = threadIdx.x;
    const int kgrp   = blockIdx.x & (NKGRP - 1);
    const int b      = blockIdx.x >> 3;
    const int strip0 = kgrp * S_PER_BLK;
    const float* inb = in  + (size_t)b * (HH * WW);
    float*      outb = out + (size_t)b * (HH * WW);

    // phase 0: per-row reciprocals + zero Hxp pad rows (raw 0..15 and 96..111), written once
    if (t < HH) {
        int lo = max(t - RAD, 0), hi = min(t + RAD, HH - 1);
        inv_ch[t] = 1.0f / (float)(hi - lo + 1);
    }
    if (t < 768) {
        const int col = t >> 3;
        const int c8  = t & 7;
        const int off = col * HXS + ((c8 < 4) ? (c8 * 4) : (96 + (c8 - 4) * 4));
        *(uint4*)(Hxp + off) = make_uint4(0u, 0u, 0u, 0u);
    }

    // hoisted per-thread mappings (strip-independent)
    const int p2row = t % HH;
    const int p2seg = t / HH;                 // <12 active
    const int p3c   = t % TW;
    const int p3bnd = t / TW;                 // <10 active
    const int r0    = p3bnd * 8;
    const int xwoff = (p3c + 16) >> 1;
    const bool hiHf = (p3c & 1) != 0;

    // prologue: stage + write strip0 into Xs (cold, once per 4 strips)
    float4 g0, g1, g2;
    {
        const int c0 = strip0 * TW;
        g0 = stage_one(inb, t, c0);
        g1 = stage_one(inb, t + NT, c0);
        if (t < 512) g2 = stage_one(inb, t + 2 * NT, c0);
        xs_write(smem, t, g0);
        xs_write(smem, t + NT, g1);
        if (t < 512) xs_write(smem, t + 2 * NT, g2);
    }
    __syncthreads();

    #pragma unroll 1
    for (int i = 0; i < S_PER_BLK; ++i) {
        const int c0 = (strip0 + i) * TW;

        // ======== segment A: issue next-strip loads; prefetch P3's x; P2 compute ========
        if (i + 1 < S_PER_BLK) {
            const int cn = c0 + TW;
            g0 = stage_one(inb, t, cn);
            g1 = stage_one(inb, t + NT, cn);
            if (t < 512) g2 = stage_one(inb, t + 2 * NT, cn);
        }
        // x prefetch for P3 epilogue (reads Xs of strip i; consumed after barrier)
        uint32_t xp0, xp1, xp2, xp3, xp4, xp5, xp6, xp7;
        if (t < 960) {
            xp0 = smem[(r0 + 0) * XSW + xwoff];
            xp1 = smem[(r0 + 1) * XSW + xwoff];
            xp2 = smem[(r0 + 2) * XSW + xwoff];
            xp3 = smem[(r0 + 3) * XSW + xwoff];
            xp4 = smem[(r0 + 4) * XSW + xwoff];
            xp5 = smem[(r0 + 5) * XSW + xwoff];
            xp6 = smem[(r0 + 6) * XSW + xwoff];
            xp7 = smem[(r0 + 7) * XSW + xwoff];
        }
        // P2: fused horizontal 33-tap sums of x AND x^2; bf16-packed (Sx,Sxx) per col.
        if (p2seg < 12) {
            const uint32_t* xr = smem + p2row * XSW + p2seg * 4;
            uint4 v0 = *(const uint4*)(xr);
            uint4 v1 = *(const uint4*)(xr + 4);
            uint4 v2 = *(const uint4*)(xr + 8);
            uint4 v3 = *(const uint4*)(xr + 12);
            uint4 v4 = *(const uint4*)(xr + 16);
            float l16 = bflo(W20(16));
            f32x2 pA; pA.x = l16;       pA.y = 0.f;
            f32x2 qA; qA.x = l16 * l16; qA.y = 0.f;
            f32x2 pB; pB.x = 0.f; pB.y = 0.f;
            f32x2 qB; qB.x = 0.f; qB.y = 0.f;
            #pragma unroll
            for (int q = 0; q < 16; q += 2) {
                f32x2 uA = uw(W20(q));
                f32x2 uB = uw(W20(q + 1));
                pA += uA;      pB += uB;
                qA += uA * uA; qB += uB * uB;
            }
            f32x2 ps = pA + pB, qs = qA + qB;
            float ax  = ps.x + ps.y;
            float axx = qs.x + qs.y;
            uint32_t* hw = Hxp + (p2seg * 8) * HXS + p2row + 16;
            #pragma unroll
            for (int k = 0; k < 4; ++k) {
                uint32_t wS = W20(k), wE = W20(k + 16);
                float lS = bflo(wS), hE = bfhi(wE);
                float a1x  = ax - lS + hE;
                float a1xx = axx - lS * lS + hE * hE;
                hw[(2 * k) * HXS]     = packbf2(ax, axx);
                hw[(2 * k + 1) * HXS] = packbf2(a1x, a1xx);
                if (k != 3) {
                    float hS = bfhi(wS), lN = bflo(W20(k + 17));
                    ax  = a1x - hS + lN;
                    axx = a1xx - hS * hS + lN * lN;
                }
            }
        }
        __syncthreads();

        // ======== segment B: write next strip's Xs (frees staged regs); P3 compute ========
        if (i + 1 < S_PER_BLK) {
            xs_write(smem, t, g0);
            xs_write(smem, t + NT, g1);
            if (t < 512) xs_write(smem, t + 2 * NT, g2);
        }
        // P3: vertical 33-tap sums of (Sx,Sxx) via pk_add; normalize; f32 store.
        const int gc = c0 + p3c;
        if (p3bnd < 10 && gc < WW) {
            const uint32_t* hp = Hxp + p3c * HXS + r0;   // raw rows r0 .. r0+39
            uint4 v0 = *(const uint4*)(hp);
            uint4 v1 = *(const uint4*)(hp + 4);
            uint4 v2 = *(const uint4*)(hp + 8);
            uint4 v3 = *(const uint4*)(hp + 12);
            uint4 v4 = *(const uint4*)(hp + 16);
            uint4 v5 = *(const uint4*)(hp + 20);
            uint4 v6 = *(const uint4*)(hp + 24);
            uint4 v7 = *(const uint4*)(hp + 28);
            uint4 v8 = *(const uint4*)(hp + 32);
            uint4 v9 = *(const uint4*)(hp + 36);
            f32x2 aA = uw(W40(32));
            f32x2 aB; aB.x = 0.f; aB.y = 0.f;
            #pragma unroll
            for (int q = 0; q < 32; q += 2) {
                aA += uw(W40(q));
                aB += uw(W40(q + 1));
            }
            f32x2 acc = aA + aB;                       // {Sx_v, Sxx_v}
            const float icw = 1.0f / (float)(min(gc + RAD, WW - 1) - max(gc - RAD, 0) + 1);
            f32x4 f4a = *(const f32x4*)(inv_ch + r0);
            f32x4 f4b = *(const f32x4*)(inv_ch + r0 + 4);
            #pragma unroll
            for (int k = 0; k < 8; ++k) {
                const int r = r0 + k;
                const float ninv = E4(k < 4 ? f4a : f4b, k & 3) * icw;
                f32x2 me = acc * ninv;                 // {mean, E[x^2]} via v_pk_mul
                float var = fmaxf(me.y - me.x * me.x, 1e-24f);
#if defined(__has_builtin) && __has_builtin(__builtin_amdgcn_rsqf)
                float isd = __builtin_amdgcn_rsqf(var);
#else
                float isd = __builtin_amdgcn_rcpf(__builtin_amdgcn_sqrtf(var) + EPSF);
#endif
                uint32_t xw = XP(k);
                float xv = hiHf ? bfhi(xw) : bflo(xw);
                outb[(size_t)r * WW + gc] = (xv - me.x) * isd;
                if (k != 7) {
                    acc += uw(W40(k + 33)) - uw(W40(k));   // 2x v_pk_add_f32
                }
            }
        }
        if (i + 1 < S_PER_BLK) __syncthreads();
    }
}

extern "C" void kernel_launch(void* const* d_in, const int* in_sizes, int n_in,
                              void* d_out, int out_size, void* d_ws, size_t ws_size,
                              hipStream_t stream) {
    const float* in = (const float*)d_in[0];
    float* out = (float*)d_out;

    const size_t lds_bytes = (size_t)TOT_WORDS * sizeof(uint32_t);  // 66624
    static bool attr_set = false;
    if (!attr_set) {
        (void)hipFuncSetAttribute((const void*)localnorm_kernel,
                                  hipFuncAttributeMaxDynamicSharedMemorySize,
                                  (int)lds_bytes);
        attr_set = true;
    }

    dim3 grid(BB * NKGRP);   // 512 blocks = exactly 2 resident per CU
    dim3 block(NT);
    localnorm_kernel<<<grid, block, lds_bytes, stream>>>(in, out);
}

// Round 8
// 59.336 us; speedup vs baseline: 1.1428x; 1.1428x over previous
//
#include <hip/hip_runtime.h>
#include <hip/hip_bf16.h>
#include <math.h>

#define BB 64
#define HH 80
#define WW 3000
#define RAD 16
#define TW 96             // output columns per strip
#define HXS 116           // Hxp col stride: 112 raw rows + 4 pad (116 % 32 == 20 -> b128 bank-spread)
#define NSTRIP 32         // ceil(3000/96)
#define NT 1024
#define EPSF 1e-8f

#define HXP_WORDS (TW * HXS)            // 11136
#define ICH_OFF  HXP_WORDS              // 11136
#define TOT_WORDS (ICH_OFF + HH)        // 11216 words = 44864 B -> 2 blocks/CU (32/32 wave slots)

typedef float f32x2 __attribute__((ext_vector_type(2)));
typedef float f32x4 __attribute__((ext_vector_type(4)));

__device__ __forceinline__ float bflo(uint32_t w) { return __uint_as_float(w << 16); }
__device__ __forceinline__ float bfhi(uint32_t w) { return __uint_as_float(w & 0xffff0000u); }
__device__ __forceinline__ uint32_t packbf2(float lo, float hi) {
    union { __hip_bfloat162 h2; uint32_t u; } u;
    u.h2 = __hip_bfloat162(__float2bfloat16(lo), __float2bfloat16(hi));
    return u.u;
}
// unpack a bf16-packed word into f32x2 {lo, hi}; pk_add accumulates both halves
__device__ __forceinline__ f32x2 uw(uint32_t w) {
    f32x2 r; r.x = bflo(w); r.y = bfhi(w); return r;
}

// compile-time-folding element selectors (named registers only — no arrays/unions)
#define E4(V, J) ((J) == 0 ? (V).x : ((J) == 1 ? (V).y : ((J) == 2 ? (V).z : (V).w)))
#define F40(Q) E4((Q) < 4 ? g0 : (Q) < 8 ? g1 : (Q) < 12 ? g2 : (Q) < 16 ? g3 : (Q) < 20 ? g4 : \
                  (Q) < 24 ? g5 : (Q) < 28 ? g6 : (Q) < 32 ? g7 : (Q) < 36 ? g8 : g9, (Q) & 3)
#define W40(Q) E4((Q) < 4 ? v0 : (Q) < 8 ? v1 : (Q) < 12 ? v2 : (Q) < 16 ? v3 : (Q) < 20 ? v4 : \
                  (Q) < 24 ? v5 : (Q) < 28 ? v6 : (Q) < 32 ? v7 : (Q) < 36 ? v8 : v9, (Q) & 3)

__global__ __launch_bounds__(NT, 8)
void localnorm_kernel(const float* __restrict__ in, float* __restrict__ out) {
    extern __shared__ uint32_t smem[];
    uint32_t* Hxp = smem;                    // Hxp[col][raw_r] at col*HXS + raw_r; raw_r = logical+16
    float* inv_ch = (float*)(smem + ICH_OFF);

    const int t     = threadIdx.x;
    const int strip = blockIdx.x % NSTRIP;
    const int b     = blockIdx.x / NSTRIP;
    const int c0    = strip * TW;
    const float* inb = in + (size_t)b * (HH * WW);

    // phase 0: per-row reciprocals + zero Hxp pad rows (raw 0..15 and 96..111) for all 96 cols
    if (t < HH) {
        int lo = max(t - RAD, 0), hi = min(t + RAD, HH - 1);
        inv_ch[t] = 1.0f / (float)(hi - lo + 1);
    }
    if (t < 768) {
        const int col = t >> 3;
        const int c8  = t & 7;
        const int off = col * HXS + ((c8 < 4) ? (c8 * 4) : (96 + (c8 - 4) * 4));
        *(uint4*)(Hxp + off) = make_uint4(0u, 0u, 0u, 0u);
    }

    // phase 2: horizontal 33-tap (Sx,Sxx) straight from GLOBAL (f32, register window).
    // 80 rows x 12 segs of 8 cols = 960 threads; 10 float4 global loads each.
    {
        const int row = t % HH;
        const int seg = t / HH;
        if (seg < 12) {
            const int gb = c0 - 16 + 8 * seg;       // first loaded col (global)
            const float* rp = inb + (size_t)row * WW;
            f32x4 g0, g1, g2, g3, g4, g5, g6, g7, g8, g9;
            if (gb >= 0 && gb + 40 <= WW) {
                g0 = *(const f32x4*)(rp + gb);
                g1 = *(const f32x4*)(rp + gb + 4);
                g2 = *(const f32x4*)(rp + gb + 8);
                g3 = *(const f32x4*)(rp + gb + 12);
                g4 = *(const f32x4*)(rp + gb + 16);
                g5 = *(const f32x4*)(rp + gb + 20);
                g6 = *(const f32x4*)(rp + gb + 24);
                g7 = *(const f32x4*)(rp + gb + 28);
                g8 = *(const f32x4*)(rp + gb + 32);
                g9 = *(const f32x4*)(rp + gb + 36);
            } else {
                #define LDG1(C) (((C) >= 0 && (C) < WW) ? rp[(C)] : 0.f)
                #define GV4(V, CB) { V.x = LDG1(CB); V.y = LDG1((CB)+1); V.z = LDG1((CB)+2); V.w = LDG1((CB)+3); }
                GV4(g0, gb)      GV4(g1, gb + 4)  GV4(g2, gb + 8)  GV4(g3, gb + 12)
                GV4(g4, gb + 16) GV4(g5, gb + 20) GV4(g6, gb + 24) GV4(g7, gb + 28)
                GV4(g8, gb + 32) GV4(g9, gb + 36)
                #undef GV4
                #undef LDG1
            }
            // initial window (col 0 of this seg): elements 0..32, 2-way ILP split
            float e32 = F40(32);
            float axA = e32, axB = 0.f;
            float qxA = e32 * e32, qxB = 0.f;
            #pragma unroll
            for (int q = 0; q < 32; q += 2) {
                float fa = F40(q), fb = F40(q + 1);
                axA += fa;                 axB += fb;
                qxA = fmaf(fa, fa, qxA);   qxB = fmaf(fb, fb, qxB);
            }
            float ax = axA + axB, axx = qxA + qxB;
            uint32_t* hw = Hxp + (seg * 8) * HXS + row + 16;
            #pragma unroll
            for (int j = 0; j < 8; ++j) {
                hw[j * HXS] = packbf2(ax, axx);
                if (j != 7) {
                    float fs = F40(j), fe = F40(j + 33);
                    ax += fe - fs;
                    axx = fmaf(fe, fe, axx);
                    axx = fmaf(-fs, fs, axx);
                }
            }
        }
    }
    __syncthreads();

    // phase 3: vertical 33-tap sums of (Sx,Sxx) via pk_add; normalize with x re-read from
    // global (L1/L2-hot); f32 store. 96 cols x 10 bands of 8 rows = 960 threads.
    {
        const int c    = t % TW;
        const int band = t / TW;
        const int gc   = c0 + c;
        if (band < 10 && gc < WW) {
            const int r0 = band * 8;
            const uint32_t* hp = Hxp + c * HXS + r0;   // raw rows r0 .. r0+39
            uint4 v0 = *(const uint4*)(hp);
            uint4 v1 = *(const uint4*)(hp + 4);
            uint4 v2 = *(const uint4*)(hp + 8);
            uint4 v3 = *(const uint4*)(hp + 12);
            uint4 v4 = *(const uint4*)(hp + 16);
            uint4 v5 = *(const uint4*)(hp + 20);
            uint4 v6 = *(const uint4*)(hp + 24);
            uint4 v7 = *(const uint4*)(hp + 28);
            uint4 v8 = *(const uint4*)(hp + 32);
            uint4 v9 = *(const uint4*)(hp + 36);
            // init acc = sum of words 0..32 (3 ops/word via pk_add), 2-way split
            f32x2 aA = uw(W40(32));
            f32x2 aB; aB.x = 0.f; aB.y = 0.f;
            #pragma unroll
            for (int q = 0; q < 32; q += 2) {
                aA += uw(W40(q));
                aB += uw(W40(q + 1));
            }
            f32x2 acc = aA + aB;                       // {Sx_v, Sxx_v}
            const float icw = 1.0f / (float)(min(gc + RAD, WW - 1) - max(gc - RAD, 0) + 1);
            f32x4 f4a = *(const f32x4*)(inv_ch + r0);
            f32x4 f4b = *(const f32x4*)(inv_ch + r0 + 4);
            const float* xin  = inb + gc;
            float*       outb = out + (size_t)b * (HH * WW) + gc;
            #pragma unroll
            for (int k = 0; k < 8; ++k) {
                const int r = r0 + k;
                const float ninv = E4(k < 4 ? f4a : f4b, k & 3) * icw;
                f32x2 me = acc * ninv;                 // {mean, E[x^2]} via v_pk_mul
                float var = fmaxf(me.y - me.x * me.x, 1e-24f);
#if defined(__has_builtin) && __has_builtin(__builtin_amdgcn_rsqf)
                float isd = __builtin_amdgcn_rsqf(var);
#else
                float isd = __builtin_amdgcn_rcpf(__builtin_amdgcn_sqrtf(var) + EPSF);
#endif
                float xv = xin[(size_t)r * WW];
                outb[(size_t)r * WW] = (xv - me.x) * isd;
                if (k != 7) {
                    acc += uw(W40(k + 33)) - uw(W40(k));   // 2x v_pk_add_f32
                }
            }
        }
    }
}

extern "C" void kernel_launch(void* const* d_in, const int* in_sizes, int n_in,
                              void* d_out, int out_size, void* d_ws, size_t ws_size,
                              hipStream_t stream) {
    const float* in = (const float*)d_in[0];
    float* out = (float*)d_out;

    const size_t lds_bytes = (size_t)TOT_WORDS * sizeof(uint32_t);  // 44864
    static bool attr_set = false;
    if (!attr_set) {
        (void)hipFuncSetAttribute((const void*)localnorm_kernel,
                                  hipFuncAttributeMaxDynamicSharedMemorySize,
                                  (int)lds_bytes);
        attr_set = true;
    }

    dim3 grid(BB * NSTRIP);
    dim3 block(NT);
    localnorm_kernel<<<grid, block, lds_bytes, stream>>>(in, out);
}

// Round 9
// 44.383 us; speedup vs baseline: 1.5279x; 1.3369x over previous
//
#include <hip/hip_runtime.h>
#include <hip/hip_bf16.h>
#include <math.h>

#define BB 64
#define HH 80
#define WW 3000
#define RAD 16
#define TW 48             // output columns per strip
#define NLOAD 80          // loaded columns = TW + 2*16 halo
#define XSW 44            // Xs words/row: 40 data + 4 pad (44 % 32 == 12 -> b128 bank-spread)
#define HXS 116           // Hxp col stride: 112 raw rows + 4 pad (116 % 32 == 20 -> b128 bank-spread)
#define NSTRIP 63         // ceil(3000/48)
#define NT 512
#define EPSF 1e-8f

#define XS_WORDS (HH * XSW)             // 3520
#define HXP_OFF  XS_WORDS
#define HXP_WORDS (TW * HXS)            // 5568
#define ICH_OFF  (XS_WORDS + HXP_WORDS) // 9088
#define TOT_WORDS (ICH_OFF + HH)        // 9168 words = 36672 B -> 4 blocks/CU (32/32 wave slots)

typedef float f32x2 __attribute__((ext_vector_type(2)));
typedef float f32x4 __attribute__((ext_vector_type(4)));

__device__ __forceinline__ float bflo(uint32_t w) { return __uint_as_float(w << 16); }
__device__ __forceinline__ float bfhi(uint32_t w) { return __uint_as_float(w & 0xffff0000u); }
__device__ __forceinline__ uint32_t packbf2(float lo, float hi) {
    union { __hip_bfloat162 h2; uint32_t u; } u;
    u.h2 = __hip_bfloat162(__float2bfloat16(lo), __float2bfloat16(hi));
    return u.u;
}
// unpack a bf16-packed word into f32x2 {lo, hi}; pk_add accumulates both halves
__device__ __forceinline__ f32x2 uw(uint32_t w) {
    f32x2 r; r.x = bflo(w); r.y = bfhi(w); return r;
}

// compile-time-folding element selectors (named registers only — no arrays/unions)
#define E4(V, J) ((J) == 0 ? (V).x : ((J) == 1 ? (V).y : ((J) == 2 ? (V).z : (V).w)))
#define W20(Q) E4((Q) < 4 ? v0 : (Q) < 8 ? v1 : (Q) < 12 ? v2 : (Q) < 16 ? v3 : v4, (Q) & 3)
#define W40(Q) E4((Q) < 4 ? v0 : (Q) < 8 ? v1 : (Q) < 12 ? v2 : (Q) < 16 ? v3 : (Q) < 20 ? v4 : \
                  (Q) < 24 ? v5 : (Q) < 28 ? v6 : (Q) < 32 ? v7 : (Q) < 36 ? v8 : v9, (Q) & 3)

__global__ __launch_bounds__(NT, 8)
void localnorm_kernel(const float* __restrict__ in, float* __restrict__ out) {
    extern __shared__ uint32_t smem[];
    uint32_t* Hxp = smem + HXP_OFF;          // Hxp[col][raw_r] at col*HXS + raw_r; raw_r = logical+16
    float* inv_ch = (float*)(smem + ICH_OFF);

    const int t     = threadIdx.x;
    const int strip = blockIdx.x % NSTRIP;
    const int b     = blockIdx.x / NSTRIP;
    const int c0    = strip * TW;

    // phase 0: per-row reciprocals + zero Hxp pad rows (raw 0..15 and 96..111) for 48 cols
    if (t < HH) {
        int lo = max(t - RAD, 0), hi = min(t + RAD, HH - 1);
        inv_ch[t] = 1.0f / (float)(hi - lo + 1);
    }
    if (t < 384) {
        const int col = t >> 3;
        const int c8  = t & 7;
        const int off = col * HXS + ((c8 < 4) ? (c8 * 4) : (96 + (c8 - 4) * 4));
        *(uint4*)(Hxp + off) = make_uint4(0u, 0u, 0u, 0u);
    }

    // phase 1: load 80 cols x 80 rows, pack to bf16 pairs. 80 rows x 20 quads = 1600 tasks.
    {
        const float* inb = in + (size_t)b * (HH * WW);
        #pragma unroll
        for (int it = 0; it < 4; ++it) {
            const int id = t + it * NT;
            if (it < 3 || id < 1600) {
                const int row = id / 20;
                const int q   = id - row * 20;
                const int gc  = c0 - 16 + 4 * q;
                uint2 w2;
                if (gc >= 0 && gc + 4 <= WW) {
                    float4 v = *(const float4*)(inb + (size_t)row * WW + gc);
                    w2.x = packbf2(v.x, v.y);
                    w2.y = packbf2(v.z, v.w);
                } else {
                    float p0 = (gc     >= 0 && gc     < WW) ? inb[(size_t)row * WW + gc]     : 0.f;
                    float p1 = (gc + 1 >= 0 && gc + 1 < WW) ? inb[(size_t)row * WW + gc + 1] : 0.f;
                    float p2 = (gc + 2 >= 0 && gc + 2 < WW) ? inb[(size_t)row * WW + gc + 2] : 0.f;
                    float p3 = (gc + 3 >= 0 && gc + 3 < WW) ? inb[(size_t)row * WW + gc + 3] : 0.f;
                    w2.x = packbf2(p0, p1);
                    w2.y = packbf2(p2, p3);
                }
                *(uint2*)(smem + row * XSW + 2 * q) = w2;
            }
        }
    }
    __syncthreads();

    // phase 2: fused horizontal 33-tap sums of x AND x^2; bf16-packed (Sx,Sxx) word per col.
    // 80 rows x 6 segs of 8 cols = 480 threads; 5 b128 reads each.
    {
        const int row = t % HH;
        const int seg = t / HH;       // active < 6
        if (seg < 6) {
            const uint32_t* xr = smem + row * XSW + seg * 4;
            uint4 v0 = *(const uint4*)(xr);
            uint4 v1 = *(const uint4*)(xr + 4);
            uint4 v2 = *(const uint4*)(xr + 8);
            uint4 v3 = *(const uint4*)(xr + 12);
            uint4 v4 = *(const uint4*)(xr + 16);
            // initial window e0..e32: packed pair accumulate, 2-way ILP split
            float l16 = bflo(W20(16));
            f32x2 pA; pA.x = l16;       pA.y = 0.f;
            f32x2 qA; qA.x = l16 * l16; qA.y = 0.f;
            f32x2 pB; pB.x = 0.f; pB.y = 0.f;
            f32x2 qB; qB.x = 0.f; qB.y = 0.f;
            #pragma unroll
            for (int q = 0; q < 16; q += 2) {
                f32x2 uA = uw(W20(q));
                f32x2 uB = uw(W20(q + 1));
                pA += uA;      pB += uB;
                qA += uA * uA; qB += uB * uB;
            }
            f32x2 ps = pA + pB, qs = qA + qB;
            float ax  = ps.x + ps.y;
            float axx = qs.x + qs.y;
            uint32_t* hw = Hxp + (seg * 8) * HXS + row + 16;
            #pragma unroll
            for (int k = 0; k < 4; ++k) {
                uint32_t wS = W20(k), wE = W20(k + 16);
                float lS = bflo(wS), hE = bfhi(wE);
                float a1x  = ax - lS + hE;
                float a1xx = axx - lS * lS + hE * hE;
                hw[(2 * k) * HXS]     = packbf2(ax, axx);
                hw[(2 * k + 1) * HXS] = packbf2(a1x, a1xx);
                if (k != 3) {
                    float hS = bfhi(wS), lN = bflo(W20(k + 17));
                    ax  = a1x - hS + lN;
                    axx = a1xx - hS * hS + lN * lN;
                }
            }
        }
    }
    __syncthreads();

    // phase 3: vertical 33-tap sums of (Sx,Sxx) via pk_add; normalize, f32 store.
    // 48 cols x 10 bands of 8 rows = 480 threads; 10 contiguous b128 reads.
    {
        const int c    = t % TW;
        const int band = t / TW;      // active < 10
        const int gc   = c0 + c;
        if (band < 10 && gc < WW) {
            const int r0 = band * 8;
            const uint32_t* hp = Hxp + c * HXS + r0;   // raw rows r0 .. r0+39
            uint4 v0 = *(const uint4*)(hp);
            uint4 v1 = *(const uint4*)(hp + 4);
            uint4 v2 = *(const uint4*)(hp + 8);
            uint4 v3 = *(const uint4*)(hp + 12);
            uint4 v4 = *(const uint4*)(hp + 16);
            uint4 v5 = *(const uint4*)(hp + 20);
            uint4 v6 = *(const uint4*)(hp + 24);
            uint4 v7 = *(const uint4*)(hp + 28);
            uint4 v8 = *(const uint4*)(hp + 32);
            uint4 v9 = *(const uint4*)(hp + 36);
            // init acc = sum of words 0..32 (3 ops/word via pk_add), 2-way split
            f32x2 aA = uw(W40(32));
            f32x2 aB; aB.x = 0.f; aB.y = 0.f;
            #pragma unroll
            for (int q = 0; q < 32; q += 2) {
                aA += uw(W40(q));
                aB += uw(W40(q + 1));
            }
            f32x2 acc = aA + aB;                       // {Sx_v, Sxx_v}
            const float icw = 1.0f / (float)(min(gc + RAD, WW - 1) - max(gc - RAD, 0) + 1);
            f32x4 f4a = *(const f32x4*)(inv_ch + r0);
            f32x4 f4b = *(const f32x4*)(inv_ch + r0 + 4);
            const int  xwoff  = (c + 16) >> 1;
            const bool hiHf   = (c & 1) != 0;
            float* outb = out + (size_t)b * (HH * WW);
            #pragma unroll
            for (int k = 0; k < 8; ++k) {
                const int r = r0 + k;
                const float ninv = E4(k < 4 ? f4a : f4b, k & 3) * icw;
                f32x2 me = acc * ninv;                 // {mean, E[x^2]} via v_pk_mul
                float var = fmaxf(me.y - me.x * me.x, 1e-24f);
#if defined(__has_builtin) && __has_builtin(__builtin_amdgcn_rsqf)
                float isd = __builtin_amdgcn_rsqf(var);
#else
                float isd = __builtin_amdgcn_rcpf(__builtin_amdgcn_sqrtf(var) + EPSF);
#endif
                uint32_t xw = smem[r * XSW + xwoff];
                float xv = hiHf ? bfhi(xw) : bflo(xw);
                outb[(size_t)r * WW + gc] = (xv - me.x) * isd;
                if (k != 7) {
                    acc += uw(W40(k + 33)) - uw(W40(k));   // 2x v_pk_add_f32
                }
            }
        }
    }
}

extern "C" void kernel_launch(void* const* d_in, const int* in_sizes, int n_in,
                              void* d_out, int out_size, void* d_ws, size_t ws_size,
                              hipStream_t stream) {
    const float* in = (const float*)d_in[0];
    float* out = (float*)d_out;

    const size_t lds_bytes = (size_t)TOT_WORDS * sizeof(uint32_t);  // 36672
    static bool attr_set = false;
    if (!attr_set) {
        (void)hipFuncSetAttribute((const void*)localnorm_kernel,
                                  hipFuncAttributeMaxDynamicSharedMemorySize,
                                  (int)lds_bytes);
        attr_set = true;
    }

    dim3 grid(BB * NSTRIP);   // 4032 blocks; 4 resident per CU
    dim3 block(NT);
    localnorm_kernel<<<grid, block, lds_bytes, stream>>>(in, out);
}

// Round 10
// 39.528 us; speedup vs baseline: 1.7155x; 1.1228x over previous
//
#include <hip/hip_runtime.h>
#include <hip/hip_bf16.h>
#include <math.h>

#define BB 64
#define HH 80
#define WW 3000
#define RAD 16
#define TW 96             // output columns per strip
#define XSW 68            // Xs words/row: 64 data + 4 pad (68 % 32 == 4 -> b128 bank-spread)
#define HXS 116           // Hxp col stride: 112 raw rows + 4 pad (116 % 32 == 20 -> b128 bank-spread)
#define NSTRIP 32         // ceil(3000/96)
#define NT 1024
#define EPSF 1e-8f

#define XS_WORDS (HH * XSW)             // 5440
#define HXP_OFF  XS_WORDS
#define HXP_WORDS (TW * HXS)            // 11136
#define ICH_OFF  (XS_WORDS + HXP_WORDS) // 16576
#define TOT_WORDS (ICH_OFF + HH)        // 16656 words = 66624 B -> 2 blocks/CU (32/32 wave slots)

typedef float f32x2 __attribute__((ext_vector_type(2)));
typedef float f32x4 __attribute__((ext_vector_type(4)));

__device__ __forceinline__ float bflo(uint32_t w) { return __uint_as_float(w << 16); }
__device__ __forceinline__ float bfhi(uint32_t w) { return __uint_as_float(w & 0xffff0000u); }
__device__ __forceinline__ uint32_t packbf2(float lo, float hi) {
    union { __hip_bfloat162 h2; uint32_t u; } u;
    u.h2 = __hip_bfloat162(__float2bfloat16(lo), __float2bfloat16(hi));
    return u.u;
}
// unpack a bf16-packed word into f32x2 {lo, hi}; pk_add accumulates both halves
__device__ __forceinline__ f32x2 uw(uint32_t w) {
    f32x2 r; r.x = bflo(w); r.y = bfhi(w); return r;
}

// compile-time-folding element selectors (named registers only — no arrays/unions)
#define E4(V, J) ((J) == 0 ? (V).x : ((J) == 1 ? (V).y : ((J) == 2 ? (V).z : (V).w)))
#define W20(Q) E4((Q) < 4 ? v0 : (Q) < 8 ? v1 : (Q) < 12 ? v2 : (Q) < 16 ? v3 : v4, (Q) & 3)
#define W48(Q) E4((Q) < 4 ? R0 : (Q) < 8 ? R1 : (Q) < 12 ? R2 : (Q) < 16 ? R3 : (Q) < 20 ? R4 : \
                  (Q) < 24 ? R5 : (Q) < 28 ? R6 : (Q) < 32 ? R7 : (Q) < 36 ? R8 : \
                  (Q) < 40 ? R9 : (Q) < 44 ? R10 : R11, (Q) & 3)

__global__ __launch_bounds__(NT, 8)
void localnorm_kernel(const float* __restrict__ in, float* __restrict__ out) {
    extern __shared__ uint32_t smem[];
    uint32_t* Hxp = smem + HXP_OFF;          // Hxp[col][raw_r] at col*HXS + raw_r; raw_r = logical+16
    float* inv_ch = (float*)(smem + ICH_OFF);

    const int t     = threadIdx.x;
    const int strip = blockIdx.x % NSTRIP;
    const int b     = blockIdx.x / NSTRIP;
    const int c0    = strip * TW;
    const float* inb = in + (size_t)b * (HH * WW);

    // phase 0: per-row reciprocals + zero Hxp pad rows (raw 0..15 and 96..111) for all 96 cols.
    // Pad rows are disjoint from P2's writes (raw 16..95); read only after the barrier.
    if (t < HH) {
        int lo = max(t - RAD, 0), hi = min(t + RAD, HH - 1);
        inv_ch[t] = 1.0f / (float)(hi - lo + 1);
    }
    if (t < 768) {
        const int col = t >> 3;
        const int c8  = t & 7;
        const int off = col * HXS + ((c8 < 4) ? (c8 * 4) : (96 + (c8 - 4) * 4));
        *(uint4*)(Hxp + off) = make_uint4(0u, 0u, 0u, 0u);
    }

    const int w    = t >> 6;      // wave 0..15; owns rows 5w..5w+4 through P1+P2
    const int lane = t & 63;

    // ---- P1 (wave-private, NO barrier after): load 5 rows x 128 cols, pack bf16 -> Xs.
    // 5 rows x 32 quads = 160 tasks per wave.
    {
        #pragma unroll
        for (int i = 0; i < 3; ++i) {
            const int task = i * 64 + lane;
            if (i < 2 || task < 160) {
                const int row = 5 * w + (task >> 5);
                const int q   = task & 31;
                const int gc  = c0 - 16 + 4 * q;
                uint2 w2;
                if (gc >= 0 && gc + 4 <= WW) {
                    float4 v = *(const float4*)(inb + (size_t)row * WW + gc);
                    w2.x = packbf2(v.x, v.y);
                    w2.y = packbf2(v.z, v.w);
                } else {
                    float p0 = (gc     >= 0 && gc     < WW) ? inb[(size_t)row * WW + gc]     : 0.f;
                    float p1 = (gc + 1 >= 0 && gc + 1 < WW) ? inb[(size_t)row * WW + gc + 1] : 0.f;
                    float p2 = (gc + 2 >= 0 && gc + 2 < WW) ? inb[(size_t)row * WW + gc + 2] : 0.f;
                    float p3 = (gc + 3 >= 0 && gc + 3 < WW) ? inb[(size_t)row * WW + gc + 3] : 0.f;
                    w2.x = packbf2(p0, p1);
                    w2.y = packbf2(p2, p3);
                }
                *(uint2*)(smem + row * XSW + 2 * q) = w2;
            }
        }
    }

    // ---- P2 (same wave, same rows; lgkmcnt orders the Xs write->read, no __syncthreads):
    // fused horizontal 33-tap sums of x AND x^2. 5 rows x 12 segs = 60 of 64 lanes.
    if (lane < 60) {
        const int row = 5 * w + lane / 12;
        const int seg = lane % 12;
        const uint32_t* xr = smem + row * XSW + seg * 4;
        uint4 v0 = *(const uint4*)(xr);
        uint4 v1 = *(const uint4*)(xr + 4);
        uint4 v2 = *(const uint4*)(xr + 8);
        uint4 v3 = *(const uint4*)(xr + 12);
        uint4 v4 = *(const uint4*)(xr + 16);
        // initial window e0..e32: packed pair accumulate, 2-way ILP split
        float l16 = bflo(W20(16));
        f32x2 pA; pA.x = l16;       pA.y = 0.f;
        f32x2 qA; qA.x = l16 * l16; qA.y = 0.f;
        f32x2 pB; pB.x = 0.f; pB.y = 0.f;
        f32x2 qB; qB.x = 0.f; qB.y = 0.f;
        #pragma unroll
        for (int q = 0; q < 16; q += 2) {
            f32x2 uA = uw(W20(q));
            f32x2 uB = uw(W20(q + 1));
            pA += uA;      pB += uB;
            qA += uA * uA; qB += uB * uB;
        }
        f32x2 ps = pA + pB, qs = qA + qB;
        float ax  = ps.x + ps.y;
        float axx = qs.x + qs.y;
        uint32_t* hw = Hxp + (seg * 8) * HXS + row + 16;
        #pragma unroll
        for (int k = 0; k < 4; ++k) {
            uint32_t wS = W20(k), wE = W20(k + 16);
            float lS = bflo(wS), hE = bfhi(wE);
            float a1x  = ax - lS + hE;
            float a1xx = axx - lS * lS + hE * hE;
            hw[(2 * k) * HXS]     = packbf2(ax, axx);
            hw[(2 * k + 1) * HXS] = packbf2(a1x, a1xx);
            if (k != 3) {
                float hS = bfhi(wS), lN = bflo(W20(k + 17));
                ax  = a1x - hS + lN;
                axx = a1xx - hS * hS + lN * lN;
            }
        }
    }
    __syncthreads();   // the ONLY barrier

    // ---- P3: vertical 33-tap sums of (Sx,Sxx) via pk_add, bands of 16 rows.
    // 96 cols x 5 bands = 480 threads; 12 contiguous b128 reads (words r0..r0+47).
    {
        const int c    = t % TW;
        const int band = t / TW;
        const int gc   = c0 + c;
        if (band < 5 && gc < WW) {
            const int r0 = band * 16;
            const uint32_t* hp = Hxp + c * HXS + r0;   // raw rows r0 .. r0+47
            uint4 R0  = *(const uint4*)(hp);
            uint4 R1  = *(const uint4*)(hp + 4);
            uint4 R2  = *(const uint4*)(hp + 8);
            uint4 R3  = *(const uint4*)(hp + 12);
            uint4 R4  = *(const uint4*)(hp + 16);
            uint4 R5  = *(const uint4*)(hp + 20);
            uint4 R6  = *(const uint4*)(hp + 24);
            uint4 R7  = *(const uint4*)(hp + 28);
            uint4 R8  = *(const uint4*)(hp + 32);
            uint4 R9  = *(const uint4*)(hp + 36);
            uint4 R10 = *(const uint4*)(hp + 40);
            uint4 R11 = *(const uint4*)(hp + 44);
            // init acc = sum of words 0..32 (3 ops/word via pk_add), 2-way split
            f32x2 aA = uw(W48(32));
            f32x2 aB; aB.x = 0.f; aB.y = 0.f;
            #pragma unroll
            for (int q = 0; q < 32; q += 2) {
                aA += uw(W48(q));
                aB += uw(W48(q + 1));
            }
            f32x2 acc = aA + aB;                       // {Sx_v, Sxx_v}
            const float icw = 1.0f / (float)(min(gc + RAD, WW - 1) - max(gc - RAD, 0) + 1);
            const int  xwoff  = (c + 16) >> 1;
            const bool hiHf   = ((c + 16) & 1) != 0;
            float* outb = out + (size_t)b * (HH * WW);
            #pragma unroll
            for (int k = 0; k < 16; ++k) {
                const int r = r0 + k;
                const float ninv = inv_ch[r] * icw;
                f32x2 me = acc * ninv;                 // {mean, E[x^2]} via v_pk_mul
                float var = fmaxf(me.y - me.x * me.x, 1e-24f);
#if defined(__has_builtin) && __has_builtin(__builtin_amdgcn_rsqf)
                float isd = __builtin_amdgcn_rsqf(var);
#else
                float isd = __builtin_amdgcn_rcpf(__builtin_amdgcn_sqrtf(var) + EPSF);
#endif
                uint32_t xw = smem[r * XSW + xwoff];
                float xv = hiHf ? bfhi(xw) : bflo(xw);
                outb[(size_t)r * WW + gc] = (xv - me.x) * isd;
                if (k != 15) {
                    acc += uw(W48(k + 33)) - uw(W48(k));   // 2x v_pk_add_f32
                }
            }
        }
    }
}

extern "C" void kernel_launch(void* const* d_in, const int* in_sizes, int n_in,
                              void* d_out, int out_size, void* d_ws, size_t ws_size,
                              hipStream_t stream) {
    const float* in = (const float*)d_in[0];
    float* out = (float*)d_out;

    const size_t lds_bytes = (size_t)TOT_WORDS * sizeof(uint32_t);  // 66624
    static bool attr_set = false;
    if (!attr_set) {
        (void)hipFuncSetAttribute((const void*)localnorm_kernel,
                                  hipFuncAttributeMaxDynamicSharedMemorySize,
                                  (int)lds_bytes);
        attr_set = true;
    }

    dim3 grid(BB * NSTRIP);
    dim3 block(NT);
    localnorm_kernel<<<grid, block, lds_bytes, stream>>>(in, out);
}